// Round 3
// baseline (335.859 us; speedup 1.0000x reference)
//
#include <hip/hip_runtime.h>
#include <hip/hip_bf16.h>

#define NROW 384
#define GD   1935
#define GK   1952     // padded gate dim (61*32)
#define DD   300
#define KP   320      // padded o
#define DP   304      // padded p

// workspace offsets (in floats)
#define OFF_W    4096
#define OFF_XBF  4112      // ushort[2][384][1952]  (749568 floats)
#define OFF_EBT  753680    // ushort[320][1952]     (312320 floats)  E transposed
#define OFF_FC1B 1066000   // ushort[2][320][320]   (102400 floats)
#define OFF_FC3B 1168400   // ushort[304][320]      (48640 floats)
#define OFF_F1B  1217040   // ushort[2][384][320]   (122880 floats)
#define OFF_AB   1339920   // float[2][384][320]    Ahat | Bhat
#define OFF_CD   1585680   // float[2][384][320]    Chat | Dhat

typedef short short8 __attribute__((ext_vector_type(8)));
typedef float floatx4 __attribute__((ext_vector_type(4)));

__device__ inline unsigned short f2bf(float x){
  union { float f; unsigned u; } v; v.f = x;
  unsigned r = v.u + 0x7fffu + ((v.u >> 16) & 1u);
  return (unsigned short)(r >> 16);
}

// softmax(weight_loc) only
__global__ void k_prep(const float* wloc, float* ws){
  if (threadIdx.x == 0){
    float a = wloc[0], b = wloc[1];
    float m = fmaxf(a, b);
    float ea = expf(a - m), eb = expf(b - m);
    ws[OFF_W + 0] = ea / (ea + eb);
    ws[OFF_W + 1] = eb / (ea + eb);
  }
}

// all bf16 conversions in one pass (sigmoid inline)
#define NX  (2*384*GK)
#define NE  (KP*GK)
#define NF1 (2*KP*KP)
#define NF3 (DP*KP)
__global__ void k_cvt_all(const float* f1, const float* f2, const float* E,
                          const float* g1, const float* g2,
                          const float* fc1w, const float* fc3w, float* ws){
  int t = blockIdx.x * 256 + threadIdx.x;
  unsigned short* xbf  = (unsigned short*)(ws + OFF_XBF);
  unsigned short* ebt  = (unsigned short*)(ws + OFF_EBT);
  unsigned short* f1b  = (unsigned short*)(ws + OFF_FC1B);
  unsigned short* f3b  = (unsigned short*)(ws + OFF_FC3B);
  if (t < NX){
    int z = t / (384*GK); int r = t - z*384*GK;
    int n = r / GK, k = r - n*GK;
    const float* X = z ? f2 : f1;
    const float* g = z ? g2 : g1;
    float v = 0.f;
    if (k < GD){
      float sig = 1.f / (1.f + __expf(-g[k]));
      v = X[n*GD + k] * sig;
    }
    xbf[t] = f2bf(v);
  } else if (t < NX + NE){
    int r = t - NX;
    int c = r / GK, k = r - c*GK;
    float v = (k < GD && c < DD) ? E[k*DD + c] : 0.f;
    ebt[r] = f2bf(v);
  } else if (t < NX + NE + NF1){
    int r = t - NX - NE;
    int z = r / (KP*KP); int r2 = r - z*KP*KP;
    int o = r2 / KP, d = r2 - o*KP;
    float v = (o < DD && d < DD) ? fc1w[o*(2*DD) + z*DD + d] : 0.f;
    f1b[r] = f2bf(v);
  } else {
    int r = t - NX - NE - NF1;
    int p = r / KP, k = r - p*KP;
    float v = (p < DD && k < DD) ? fc3w[p*DD + k] : 0.f;
    f3b[r] = f2bf(v);
  }
}

// gated GEMM: f1bf[z][384][320] = Xbf @ EbtT^T, one tile per block, K split over 4 waves
__global__ __launch_bounds__(256) void k_gg(float* ws){
  int z = blockIdx.y;
  const unsigned short* X   = (const unsigned short*)(ws + OFF_XBF) + z*384*GK;
  const unsigned short* Ebt = (const unsigned short*)(ws + OFF_EBT);
  unsigned short* out       = (unsigned short*)(ws + OFF_F1B) + z*384*KP;
  int t = threadIdx.x, lane = t & 63, w = t >> 6;
  int id = blockIdx.x;                 // 0..479
  int mt = id / 20, ct = id - mt*20;
  int col = lane & 15, quad = lane >> 4;
  const unsigned short* ap = X   + (mt*16 + col)*GK + quad*8;
  const unsigned short* bp = Ebt + (ct*16 + col)*GK + quad*8;
  floatx4 acc = (floatx4){0.f,0.f,0.f,0.f};
  #pragma unroll 4
  for (int kc = w; kc < 61; kc += 4){
    short8 a = *(const short8*)(ap + kc*32);
    short8 b = *(const short8*)(bp + kc*32);
    acc = __builtin_amdgcn_mfma_f32_16x16x32_bf16(a, b, acc, 0, 0, 0);
  }
  __shared__ __align__(16) float red[4][64][4];
  *(floatx4*)&red[w][lane][0] = acc;
  __syncthreads();
  if (w == 0){
    floatx4 s = *(floatx4*)&red[0][lane][0];
    #pragma unroll
    for (int i = 1; i < 4; ++i) s += *(floatx4*)&red[i][lane][0];
    int c = ct*16 + col;
    #pragma unroll
    for (int r = 0; r < 4; ++r){
      int m = mt*16 + quad*4 + r;
      out[m*KP + c] = (c < DD) ? f2bf(s[r]) : (unsigned short)0;
    }
  }
}

// semantic: AB[z][384][320] = w0*(f1bf[z] @ fc1bf[z]^T (+b1 if z==0)); K split over 4 waves
__global__ __launch_bounds__(256) void k_sem(const float* fc1b, float* ws){
  int z = blockIdx.y;
  const unsigned short* F = (const unsigned short*)(ws + OFF_F1B) + z*384*KP;
  const unsigned short* W = (const unsigned short*)(ws + OFF_FC1B) + z*KP*KP;
  float* out = ws + OFF_AB + z*384*KP;
  float w0 = ws[OFF_W];
  int t = threadIdx.x, lane = t & 63, w = t >> 6;
  int id = blockIdx.x;
  int rt = id / 20, ot = id - rt*20;
  int col = lane & 15, quad = lane >> 4;
  const unsigned short* ap = F + (rt*16 + col)*KP + quad*8;
  const unsigned short* bp = W + (ot*16 + col)*KP + quad*8;
  floatx4 acc = (floatx4){0.f,0.f,0.f,0.f};
  #pragma unroll
  for (int kc = w; kc < 10; kc += 4){
    short8 a = *(const short8*)(ap + kc*32);
    short8 b = *(const short8*)(bp + kc*32);
    acc = __builtin_amdgcn_mfma_f32_16x16x32_bf16(a, b, acc, 0, 0, 0);
  }
  __shared__ __align__(16) float red[4][64][4];
  *(floatx4*)&red[w][lane][0] = acc;
  __syncthreads();
  if (w == 0){
    floatx4 s = *(floatx4*)&red[0][lane][0];
    #pragma unroll
    for (int i = 1; i < 4; ++i) s += *(floatx4*)&red[i][lane][0];
    int o = ot*16 + col;
    float bias = (z == 0 && o < DD) ? fc1b[o] : 0.f;
    #pragma unroll
    for (int r = 0; r < 4; ++r){
      int rr = rt*16 + quad*4 + r;
      out[rr*KP + o] = (o < DD) ? w0 * (s[r] + bias) : 0.f;
    }
  }
}

// spatial: CD[z][384][320] = w1*(box @ fc2 half (+b2 if z==0)); o>=300 -> 0
__global__ void k_spa(const float* box1, const float* box2, const float* fc2w,
                      const float* fc2b, float* ws){
  int z = blockIdx.y;
  const float* bx = z ? box2 : box1;
  float* out = ws + OFF_CD + z*384*KP;
  int joff = z ? 5 : 0;
  float w1 = ws[OFF_W + 1];
  int t = blockIdx.x * 256 + threadIdx.x;
  int r = t / KP, o = t - r*KP;
  float v = 0.f;
  if (o < DD){
    const float* b = bx + r * 5;
    const float* wr = fc2w + o * 10 + joff;
    v = b[0]*wr[0] + b[1]*wr[1] + b[2]*wr[2] + b[3]*wr[3] + b[4]*wr[4];
    if (!z) v += fc2b[o];
    v *= w1;
  }
  out[t] = v;
}

// main: out[n][m][p] = sum_o mixed(n,m,o)*fc3[p][o] + fc3b[p]
// af built in registers per-lane; weight K-slice double-buffered in LDS.
__global__ __launch_bounds__(512, 4) void k_main(const float* fc3b, float* out, const float* ws){
  __shared__ __align__(16) unsigned short swt[2][1216 * 8];
  const unsigned short* fc3bf = (const unsigned short*)(ws + OFF_FC3B);
  int t = threadIdx.x;
  int lane = t & 63, wave = t >> 6;
  int col = lane & 15, quad = lane >> 4;
  int mt0 = blockIdx.x * 128;
  int n = blockIdx.y;
  const float* Ah = ws + OFF_AB + n * KP;
  const float* Bh = ws + OFF_AB + 384 * KP;
  const float* Ch = ws + OFF_CD + n * KP;
  const float* Dh = ws + OFF_CD + 384 * KP;

  int mg = mt0 + wave*16 + col;           // this lane's A-frag m-row
  const float* pB = Bh + (size_t)mg * KP;
  const float* pD = Dh + (size_t)mg * KP;

  floatx4 acc[19];
  #pragma unroll
  for (int i = 0; i < 19; ++i) acc[i] = (floatx4){0.f,0.f,0.f,0.f};

  auto stage = [&](int buf, int kc){
    #pragma unroll
    for (int s = t; s < 1216; s += 512){
      int pt = s >> 6, l = s & 63;
      int cc = l & 15, qq = l >> 4;
      uint4 w = *(const uint4*)(fc3bf + (pt*16 + cc)*KP + kc*32 + qq*8);
      *(uint4*)&swt[buf][s * 8] = w;
    }
  };
  auto build = [&](int kc) -> short8 {
    int kb = kc*32 + quad*8;
    float4 a0 = *(const float4*)(Ah + kb),     a1 = *(const float4*)(Ah + kb + 4);
    float4 c0 = *(const float4*)(Ch + kb),     c1 = *(const float4*)(Ch + kb + 4);
    float4 b0 = *(const float4*)(pB + kb),     b1 = *(const float4*)(pB + kb + 4);
    float4 d0 = *(const float4*)(pD + kb),     d1 = *(const float4*)(pD + kb + 4);
    union { unsigned short s[8]; short8 v; } u;
    u.s[0] = f2bf(fmaxf(a0.x + b0.x, 0.f) + fmaxf(c0.x + d0.x, 0.f));
    u.s[1] = f2bf(fmaxf(a0.y + b0.y, 0.f) + fmaxf(c0.y + d0.y, 0.f));
    u.s[2] = f2bf(fmaxf(a0.z + b0.z, 0.f) + fmaxf(c0.z + d0.z, 0.f));
    u.s[3] = f2bf(fmaxf(a0.w + b0.w, 0.f) + fmaxf(c0.w + d0.w, 0.f));
    u.s[4] = f2bf(fmaxf(a1.x + b1.x, 0.f) + fmaxf(c1.x + d1.x, 0.f));
    u.s[5] = f2bf(fmaxf(a1.y + b1.y, 0.f) + fmaxf(c1.y + d1.y, 0.f));
    u.s[6] = f2bf(fmaxf(a1.z + b1.z, 0.f) + fmaxf(c1.z + d1.z, 0.f));
    u.s[7] = f2bf(fmaxf(a1.w + b1.w, 0.f) + fmaxf(c1.w + d1.w, 0.f));
    return u.v;
  };

  stage(0, 0);
  short8 af = build(0);
  __syncthreads();

  #pragma unroll 2
  for (int kc = 0; kc < 10; ++kc){
    int cur = kc & 1;
    short8 afn = af;
    if (kc < 9){
      stage(1 - cur, kc + 1);   // writes other buffer, overlaps this kc's MFMAs
      afn = build(kc + 1);
    }
    #pragma unroll
    for (int pt = 0; pt < 19; ++pt){
      short8 bf = *(const short8*)&swt[cur][(pt*64 + lane) * 8];
      acc[pt] = __builtin_amdgcn_mfma_f32_16x16x32_bf16(af, bf, acc[pt], 0, 0, 0);
    }
    af = afn;
    __syncthreads();
  }

  #pragma unroll
  for (int pt = 0; pt < 19; ++pt){
    int p = pt*16 + col;
    if (p < DD){
      float bias = fc3b[p];
      #pragma unroll
      for (int r = 0; r < 4; ++r){
        int m = mt0 + wave*16 + quad*4 + r;
        out[((size_t)n * NROW + m) * DD + p] = acc[pt][r] + bias;
      }
    }
  }
}

extern "C" void kernel_launch(void* const* d_in, const int* in_sizes, int n_in,
                              void* d_out, int out_size, void* d_ws, size_t ws_size,
                              hipStream_t stream) {
  const float* feature1 = (const float*)d_in[0];
  const float* box1     = (const float*)d_in[1];
  const float* feature2 = (const float*)d_in[2];
  const float* box2     = (const float*)d_in[3];
  const float* E        = (const float*)d_in[4];
  const float* gate1    = (const float*)d_in[5];
  const float* gate2    = (const float*)d_in[6];
  const float* wloc     = (const float*)d_in[7];
  const float* fc1w     = (const float*)d_in[8];
  const float* fc1b     = (const float*)d_in[9];
  const float* fc2w     = (const float*)d_in[10];
  const float* fc2b     = (const float*)d_in[11];
  const float* fc3w     = (const float*)d_in[12];
  const float* fc3b     = (const float*)d_in[13];
  float* out = (float*)d_out;
  float* ws  = (float*)d_ws;

  hipLaunchKernelGGL(k_prep, dim3(1), dim3(64), 0, stream, wloc, ws);
  hipLaunchKernelGGL(k_cvt_all, dim3((NX+NE+NF1+NF3)/256), dim3(256), 0, stream,
                     feature1, feature2, E, gate1, gate2, fc1w, fc3w, ws);
  hipLaunchKernelGGL(k_gg, dim3(480, 2), dim3(256), 0, stream, ws);
  hipLaunchKernelGGL(k_spa, dim3(480, 2), dim3(256), 0, stream,
                     box1, box2, fc2w, fc2b, ws);
  hipLaunchKernelGGL(k_sem, dim3(480, 2), dim3(256), 0, stream, fc1b, ws);
  hipLaunchKernelGGL(k_main, dim3(3, NROW), dim3(512), 0, stream, fc3b, out, ws);
}